// Round 1
// baseline (563.454 us; speedup 1.0000x reference)
//
#include <hip/hip_runtime.h>
#include <hip/hip_bf16.h>

// GraphSAGE 2-layer, fp32.
// Restructure: project-then-aggregate (aggregation is linear).
//   ycomb = x @ [W1l|W1r]^T          (GEMM, K=1433, 64 out cols)
//   acc   = segment_sum(ycomb[:, :32][src], tgt); cnt = degree(tgt)
//   h     = acc/max(cnt,1) + b1l + ycomb[:,32:]
//   ycomb = h @ [W2l|W2r]^T          (GEMM, K=32)
//   acc   = segment_sum(ycomb[:, :32][src], tgt)
//   out   = log_softmax(relu(acc/max(cnt,1) + b2l + ycomb[:,32:]))

#define BM 128
#define BN 64
#define BK 32

__global__ __launch_bounds__(256) void gemm2w(
    const float* __restrict__ X, const float* __restrict__ Wl,
    const float* __restrict__ Wr, float* __restrict__ Y, int Nrows, int K) {
  __shared__ float xs[BK][BM];  // k-major: xs[k][row]
  __shared__ float ws[BK][BN];  // k-major: ws[k][col]
  const int tid = threadIdx.x;
  const int row0 = blockIdx.x * BM;
  const int ty = tid >> 4;   // 0..15 -> 8-row group
  const int tx = tid & 15;   // 0..15 -> 4-col group
  float acc[8][4];
#pragma unroll
  for (int i = 0; i < 8; ++i)
#pragma unroll
    for (int j = 0; j < 4; ++j) acc[i][j] = 0.0f;

  for (int k0 = 0; k0 < K; k0 += BK) {
    // ---- stage x tile: thread loads 64B contiguous of one row ----
    {
      const int rr = tid >> 1;        // 0..127
      const int half = tid & 1;       // 0..1 -> k offset 0 / 16
      const int r = row0 + rr;
#pragma unroll
      for (int j = 0; j < 4; ++j) {
        const int k = half * 16 + j * 4;
        const int kg = k0 + k;
        float4 v = make_float4(0.f, 0.f, 0.f, 0.f);
        if (r < Nrows) {
          if (kg + 3 < K) {
            v = *reinterpret_cast<const float4*>(&X[(long)r * K + kg]);
          } else {
            float tmp[4] = {0.f, 0.f, 0.f, 0.f};
#pragma unroll
            for (int u = 0; u < 4; ++u)
              if (kg + u < K) tmp[u] = X[(long)r * K + kg + u];
            v = make_float4(tmp[0], tmp[1], tmp[2], tmp[3]);
          }
        }
        xs[k + 0][rr] = v.x;
        xs[k + 1][rr] = v.y;
        xs[k + 2][rr] = v.z;
        xs[k + 3][rr] = v.w;
      }
    }
    // ---- stage W tile: col c = tid>>2, k quarter = tid&3 ----
    {
      const int c = tid >> 2;   // 0..63
      const int kq = tid & 3;   // 0..3 -> k base kq*8
      const float* Wrow = (c < 32) ? &Wl[(long)c * K] : &Wr[(long)(c - 32) * K];
#pragma unroll
      for (int j = 0; j < 2; ++j) {
        const int k = kq * 8 + j * 4;
        const int kg = k0 + k;
        float4 v = make_float4(0.f, 0.f, 0.f, 0.f);
        if (kg + 3 < K) {
          v = *reinterpret_cast<const float4*>(&Wrow[kg]);
        } else {
          float tmp[4] = {0.f, 0.f, 0.f, 0.f};
#pragma unroll
          for (int u = 0; u < 4; ++u)
            if (kg + u < K) tmp[u] = Wrow[kg + u];
          v = make_float4(tmp[0], tmp[1], tmp[2], tmp[3]);
        }
        ws[k + 0][c] = v.x;
        ws[k + 1][c] = v.y;
        ws[k + 2][c] = v.z;
        ws[k + 3][c] = v.w;
      }
    }
    __syncthreads();
#pragma unroll
    for (int k = 0; k < BK; ++k) {
      const float4 a0 = *reinterpret_cast<const float4*>(&xs[k][ty * 8]);
      const float4 a1 = *reinterpret_cast<const float4*>(&xs[k][ty * 8 + 4]);
      const float4 b = *reinterpret_cast<const float4*>(&ws[k][tx * 4]);
      const float aa[8] = {a0.x, a0.y, a0.z, a0.w, a1.x, a1.y, a1.z, a1.w};
      const float bb[4] = {b.x, b.y, b.z, b.w};
#pragma unroll
      for (int i = 0; i < 8; ++i)
#pragma unroll
        for (int j = 0; j < 4; ++j) acc[i][j] = fmaf(aa[i], bb[j], acc[i][j]);
    }
    __syncthreads();
  }
#pragma unroll
  for (int i = 0; i < 8; ++i) {
    const int r = row0 + ty * 8 + i;
    if (r < Nrows) {
      float4 v = make_float4(acc[i][0], acc[i][1], acc[i][2], acc[i][3]);
      *reinterpret_cast<float4*>(&Y[(long)r * 64 + tx * 4]) = v;
    }
  }
}

// One thread per (edge, col). Gathers Y[src, c] (c in 0..31) and atomically
// accumulates into acc[tgt, c]. If cnt != nullptr, lane c==0 counts degree.
__global__ __launch_bounds__(256) void edge_agg(
    const int* __restrict__ ei, const float* __restrict__ Y,
    float* __restrict__ acc, float* __restrict__ cnt, int E) {
  const long t = (long)blockIdx.x * blockDim.x + threadIdx.x;
  if (t >= (long)E * 32) return;
  const int e = (int)(t >> 5);
  const int c = (int)(t & 31);
  const int src = ei[e];
  const int tgt = ei[E + e];
  const float v = Y[(long)src * 64 + c];
  atomicAdd(&acc[(long)tgt * 32 + c], v);
  if (cnt != nullptr && c == 0) atomicAdd(&cnt[tgt], 1.0f);
}

// h = acc / max(cnt,1) + b1 + Y[:, 32:64]   (one thread per 4 floats)
__global__ __launch_bounds__(256) void finalize1(
    const float* __restrict__ acc, const float* __restrict__ cnt,
    const float* __restrict__ b1, const float* __restrict__ Y,
    float* __restrict__ H, int N) {
  const int t = blockIdx.x * blockDim.x + threadIdx.x;
  if (t >= N * 8) return;
  const int i = t >> 3;
  const int q = t & 7;
  const float inv = 1.0f / fmaxf(cnt[i], 1.0f);
  const float4 a = *reinterpret_cast<const float4*>(&acc[(long)i * 32 + q * 4]);
  const float4 yr =
      *reinterpret_cast<const float4*>(&Y[(long)i * 64 + 32 + q * 4]);
  const float4 b = *reinterpret_cast<const float4*>(&b1[q * 4]);
  float4 h;
  h.x = fmaf(a.x, inv, b.x + yr.x);
  h.y = fmaf(a.y, inv, b.y + yr.y);
  h.z = fmaf(a.z, inv, b.z + yr.z);
  h.w = fmaf(a.w, inv, b.w + yr.w);
  *reinterpret_cast<float4*>(&H[(long)i * 32 + q * 4]) = h;
}

// out = log_softmax(relu(acc/max(cnt,1) + b2 + Y[:,32:64])) per 32-col row.
__global__ __launch_bounds__(256) void finalize2(
    const float* __restrict__ acc, const float* __restrict__ cnt,
    const float* __restrict__ b2, const float* __restrict__ Y,
    float* __restrict__ out, int N) {
  const int t = blockIdx.x * blockDim.x + threadIdx.x;
  if (t >= N * 32) return;
  const int i = t >> 5;
  const int c = t & 31;
  const float cn = fmaxf(cnt[i], 1.0f);
  float v = acc[(long)i * 32 + c] / cn + b2[c] + Y[(long)i * 64 + 32 + c];
  v = fmaxf(v, 0.0f);
  float m = v;
#pragma unroll
  for (int d = 16; d >= 1; d >>= 1) m = fmaxf(m, __shfl_xor(m, d));
  const float ex = __expf(v - m);
  float s = ex;
#pragma unroll
  for (int d = 16; d >= 1; d >>= 1) s += __shfl_xor(s, d);
  out[(long)i * 32 + c] = (v - m) - __logf(s);
}

extern "C" void kernel_launch(void* const* d_in, const int* in_sizes, int n_in,
                              void* d_out, int out_size, void* d_ws,
                              size_t ws_size, hipStream_t stream) {
  const float* x = (const float*)d_in[0];
  const int* ei = (const int*)d_in[1];
  const float* W1l = (const float*)d_in[2];
  const float* b1l = (const float*)d_in[3];
  const float* W1r = (const float*)d_in[4];
  const float* W2l = (const float*)d_in[5];
  const float* b2l = (const float*)d_in[6];
  const float* W2r = (const float*)d_in[7];
  float* out = (float*)d_out;

  const int K1 = 1433;
  const int N = in_sizes[0] / K1;
  const int E = in_sizes[1] / 2;

  char* ws = (char*)d_ws;
  float* ycomb = (float*)ws;                          // N*64
  float* acc = (float*)(ws + (size_t)N * 64 * 4);     // N*32
  float* h = (float*)(ws + (size_t)N * 96 * 4);       // N*32
  float* cnt = (float*)(ws + (size_t)N * 128 * 4);    // N

  hipMemsetAsync(acc, 0, (size_t)N * 32 * 4, stream);
  hipMemsetAsync(cnt, 0, (size_t)N * 4, stream);

  // Layer 1
  gemm2w<<<(N + BM - 1) / BM, 256, 0, stream>>>(x, W1l, W1r, ycomb, N, K1);
  edge_agg<<<(int)(((long)E * 32 + 255) / 256), 256, 0, stream>>>(ei, ycomb,
                                                                  acc, cnt, E);
  finalize1<<<(N * 8 + 255) / 256, 256, 0, stream>>>(acc, cnt, b1l, ycomb, h,
                                                     N);
  // Layer 2
  hipMemsetAsync(acc, 0, (size_t)N * 32 * 4, stream);
  gemm2w<<<(N + BM - 1) / BM, 256, 0, stream>>>(h, W2l, W2r, ycomb, N, 32);
  edge_agg<<<(int)(((long)E * 32 + 255) / 256), 256, 0, stream>>>(
      ei, ycomb, acc, nullptr, E);
  finalize2<<<(N * 32 + 255) / 256, 256, 0, stream>>>(acc, cnt, b2l, ycomb,
                                                      out, N);
}

// Round 2
// 413.420 us; speedup vs baseline: 1.3629x; 1.3629x over previous
//
#include <hip/hip_runtime.h>
#include <hip/hip_bf16.h>

// GraphSAGE 2-layer. Project-then-aggregate (aggregation is linear):
//   ycomb = x @ [W1l|W1r]^T   (bf16 MFMA GEMM, A loaded global->reg, no LDS)
//   acc   = segment_sum(ycomb[:, :32][src], tgt); cnt = degree(tgt)
//   h     = acc/max(cnt,1) + b1l + ycomb[:,32:]
//   ycomb = h @ [W2l|W2r]^T
//   acc   = segment_sum(ycomb[:, :32][src], tgt)
//   out   = log_softmax(relu(acc/max(cnt,1) + b2l + ycomb[:,32:]))

typedef __attribute__((ext_vector_type(8))) __bf16 bf16x8;
typedef __attribute__((ext_vector_type(4))) float f32x4;

__device__ __forceinline__ bf16x8 ld_a8(const float* p) {
  const float4 u = *reinterpret_cast<const float4*>(p);
  const float4 v = *reinterpret_cast<const float4*>(p + 4);
  bf16x8 r;
  r[0] = (__bf16)u.x; r[1] = (__bf16)u.y; r[2] = (__bf16)u.z; r[3] = (__bf16)u.w;
  r[4] = (__bf16)v.x; r[5] = (__bf16)v.y; r[6] = (__bf16)v.z; r[7] = (__bf16)v.w;
  return r;
}

// Convert [W_l; W_r] (each 32 x K fp32) into WB[64][KP] bf16, zero-padded.
__global__ __launch_bounds__(256) void conv_w(const float* __restrict__ Wl,
                                              const float* __restrict__ Wr,
                                              __bf16* __restrict__ out, int K,
                                              int KP) {
  const int t = blockIdx.x * 256 + threadIdx.x;
  if (t >= 64 * KP) return;
  const int c = t / KP, k = t - c * KP;
  float v = 0.0f;
  if (k < K) v = (c < 32) ? Wl[(long)c * K + k] : Wr[(long)(c - 32) * K + k];
  out[t] = (__bf16)v;
}

// Y[N][64] = X[N][K] @ WB[64][KP]^T. 256 thr = 4 waves; wave owns 32 rows x 64
// cols (2x4 tiles of 16x16). A: global->reg fp32->bf16, no LDS. B: bf16,
// zero-padded to KP (multiple of 8), L2-resident.
__global__ __launch_bounds__(256) void gemm_mfma(const float* __restrict__ X,
                                                 const __bf16* __restrict__ WB,
                                                 float* __restrict__ Y,
                                                 int Nrows, int K, int KP) {
  const int tid = threadIdx.x;
  const int w = tid >> 6, l = tid & 63;
  const int lr = l & 15, lg = l >> 4;
  const long rowbase = (long)blockIdx.x * 128 + (long)w * 32;
  long r0 = rowbase + lr;      if (r0 >= Nrows) r0 = Nrows - 1;
  long r1 = rowbase + 16 + lr; if (r1 >= Nrows) r1 = Nrows - 1;
  const float* px0 = X + r0 * K + lg * 8;
  const float* px1 = X + r1 * K + lg * 8;
  const __bf16* pw = WB + (long)lr * KP + lg * 8;
  const long ws16 = (long)16 * KP;

  f32x4 acc[2][4];
#pragma unroll
  for (int i = 0; i < 2; ++i)
#pragma unroll
    for (int j = 0; j < 4; ++j) acc[i][j] = (f32x4){0.f, 0.f, 0.f, 0.f};

  const int nfull = K >> 5;
  const int krem = K & 31;

  bf16x8 a0, a1, b0, b1, b2, b3;
  a0 = ld_a8(px0);
  a1 = ld_a8(px1);
  b0 = *reinterpret_cast<const bf16x8*>(pw);
  b1 = *reinterpret_cast<const bf16x8*>(pw + ws16);
  b2 = *reinterpret_cast<const bf16x8*>(pw + 2 * ws16);
  b3 = *reinterpret_cast<const bf16x8*>(pw + 3 * ws16);

#define MFMA8()                                                               \
  do {                                                                        \
    acc[0][0] = __builtin_amdgcn_mfma_f32_16x16x32_bf16(a0, b0, acc[0][0], 0, 0, 0); \
    acc[0][1] = __builtin_amdgcn_mfma_f32_16x16x32_bf16(a0, b1, acc[0][1], 0, 0, 0); \
    acc[0][2] = __builtin_amdgcn_mfma_f32_16x16x32_bf16(a0, b2, acc[0][2], 0, 0, 0); \
    acc[0][3] = __builtin_amdgcn_mfma_f32_16x16x32_bf16(a0, b3, acc[0][3], 0, 0, 0); \
    acc[1][0] = __builtin_amdgcn_mfma_f32_16x16x32_bf16(a1, b0, acc[1][0], 0, 0, 0); \
    acc[1][1] = __builtin_amdgcn_mfma_f32_16x16x32_bf16(a1, b1, acc[1][1], 0, 0, 0); \
    acc[1][2] = __builtin_amdgcn_mfma_f32_16x16x32_bf16(a1, b2, acc[1][2], 0, 0, 0); \
    acc[1][3] = __builtin_amdgcn_mfma_f32_16x16x32_bf16(a1, b3, acc[1][3], 0, 0, 0); \
  } while (0)

  for (int s = 1; s < nfull; ++s) {
    const int k0 = s * 32;
    const bf16x8 na0 = ld_a8(px0 + k0);
    const bf16x8 na1 = ld_a8(px1 + k0);
    const bf16x8 nb0 = *reinterpret_cast<const bf16x8*>(pw + k0);
    const bf16x8 nb1 = *reinterpret_cast<const bf16x8*>(pw + ws16 + k0);
    const bf16x8 nb2 = *reinterpret_cast<const bf16x8*>(pw + 2 * ws16 + k0);
    const bf16x8 nb3 = *reinterpret_cast<const bf16x8*>(pw + 3 * ws16 + k0);
    MFMA8();
    a0 = na0; a1 = na1; b0 = nb0; b1 = nb1; b2 = nb2; b3 = nb3;
  }
  MFMA8();

  if (krem) {
    const int k0 = nfull * 32;
    bf16x8 ta0, ta1;
#pragma unroll
    for (int i = 0; i < 8; ++i) {
      const int k = k0 + lg * 8 + i;
      ta0[i] = (k < K) ? (__bf16)px0[k0 + i] : (__bf16)0.0f;
      ta1[i] = (k < K) ? (__bf16)px1[k0 + i] : (__bf16)0.0f;
    }
    a0 = ta0; a1 = ta1;
    b0 = *reinterpret_cast<const bf16x8*>(pw + k0);
    b1 = *reinterpret_cast<const bf16x8*>(pw + ws16 + k0);
    b2 = *reinterpret_cast<const bf16x8*>(pw + 2 * ws16 + k0);
    b3 = *reinterpret_cast<const bf16x8*>(pw + 3 * ws16 + k0);
    MFMA8();
  }
#undef MFMA8

  // D layout: col = lane&15, row = (lane>>4)*4 + reg.
#pragma unroll
  for (int t = 0; t < 2; ++t) {
#pragma unroll
    for (int j = 0; j < 4; ++j) {
      const long R = rowbase + t * 16 + lg * 4 + j;
      if (R < Nrows) {
#pragma unroll
        for (int ct = 0; ct < 4; ++ct)
          Y[R * 64 + ct * 16 + lr] = acc[t][ct][j];
      }
    }
  }
}

// One thread per (edge, col). Gathers Y[src, c] (c in 0..31) and atomically
// accumulates into acc[tgt, c]. If cnt != nullptr, lane c==0 counts degree.
__global__ __launch_bounds__(256) void edge_agg(
    const int* __restrict__ ei, const float* __restrict__ Y,
    float* __restrict__ acc, float* __restrict__ cnt, int E) {
  const long t = (long)blockIdx.x * blockDim.x + threadIdx.x;
  if (t >= (long)E * 32) return;
  const int e = (int)(t >> 5);
  const int c = (int)(t & 31);
  const int src = ei[e];
  const int tgt = ei[E + e];
  const float v = Y[(long)src * 64 + c];
  atomicAdd(&acc[(long)tgt * 32 + c], v);
  if (cnt != nullptr && c == 0) atomicAdd(&cnt[tgt], 1.0f);
}

__global__ __launch_bounds__(256) void finalize1(
    const float* __restrict__ acc, const float* __restrict__ cnt,
    const float* __restrict__ b1, const float* __restrict__ Y,
    float* __restrict__ H, int N) {
  const int t = blockIdx.x * blockDim.x + threadIdx.x;
  if (t >= N * 8) return;
  const int i = t >> 3;
  const int q = t & 7;
  const float inv = 1.0f / fmaxf(cnt[i], 1.0f);
  const float4 a = *reinterpret_cast<const float4*>(&acc[(long)i * 32 + q * 4]);
  const float4 yr =
      *reinterpret_cast<const float4*>(&Y[(long)i * 64 + 32 + q * 4]);
  const float4 b = *reinterpret_cast<const float4*>(&b1[q * 4]);
  float4 h;
  h.x = fmaf(a.x, inv, b.x + yr.x);
  h.y = fmaf(a.y, inv, b.y + yr.y);
  h.z = fmaf(a.z, inv, b.z + yr.z);
  h.w = fmaf(a.w, inv, b.w + yr.w);
  *reinterpret_cast<float4*>(&H[(long)i * 32 + q * 4]) = h;
}

__global__ __launch_bounds__(256) void finalize2(
    const float* __restrict__ acc, const float* __restrict__ cnt,
    const float* __restrict__ b2, const float* __restrict__ Y,
    float* __restrict__ out, int N) {
  const int t = blockIdx.x * blockDim.x + threadIdx.x;
  if (t >= N * 32) return;
  const int i = t >> 5;
  const int c = t & 31;
  const float cn = fmaxf(cnt[i], 1.0f);
  float v = acc[(long)i * 32 + c] / cn + b2[c] + Y[(long)i * 64 + 32 + c];
  v = fmaxf(v, 0.0f);
  float m = v;
#pragma unroll
  for (int d = 16; d >= 1; d >>= 1) m = fmaxf(m, __shfl_xor(m, d));
  const float ex = __expf(v - m);
  float s = ex;
#pragma unroll
  for (int d = 16; d >= 1; d >>= 1) s += __shfl_xor(s, d);
  out[(long)i * 32 + c] = (v - m) - __logf(s);
}

extern "C" void kernel_launch(void* const* d_in, const int* in_sizes, int n_in,
                              void* d_out, int out_size, void* d_ws,
                              size_t ws_size, hipStream_t stream) {
  const float* x = (const float*)d_in[0];
  const int* ei = (const int*)d_in[1];
  const float* W1l = (const float*)d_in[2];
  const float* b1l = (const float*)d_in[3];
  const float* W1r = (const float*)d_in[4];
  const float* W2l = (const float*)d_in[5];
  const float* b2l = (const float*)d_in[6];
  const float* W2r = (const float*)d_in[7];
  float* out = (float*)d_out;

  const int K1 = 1433;
  const int KP1 = 1440;  // padded, multiple of 8
  const int N = in_sizes[0] / K1;
  const int E = in_sizes[1] / 2;

  char* ws = (char*)d_ws;
  float* ycomb = (float*)ws;                        // N*64 f32
  float* acc = (float*)(ws + (size_t)N * 64 * 4);   // N*32 f32
  float* h = (float*)(ws + (size_t)N * 96 * 4);     // N*32 f32
  float* cnt = (float*)(ws + (size_t)N * 128 * 4);  // N f32
  __bf16* wb1 = (__bf16*)(ws + (size_t)N * 132 * 4);          // 64*1440 bf16
  __bf16* wb2 = (__bf16*)(ws + (size_t)N * 132 * 4 + 256 * 1024);  // 64*32

  conv_w<<<(64 * KP1 + 255) / 256, 256, 0, stream>>>(W1l, W1r, wb1, K1, KP1);
  conv_w<<<(64 * 32 + 255) / 256, 256, 0, stream>>>(W2l, W2r, wb2, 32, 32);
  hipMemsetAsync(acc, 0, (size_t)N * 32 * 4, stream);
  hipMemsetAsync(cnt, 0, (size_t)N * 4, stream);

  // Layer 1
  gemm_mfma<<<(N + 127) / 128, 256, 0, stream>>>(x, wb1, ycomb, N, K1, KP1);
  edge_agg<<<(int)(((long)E * 32 + 255) / 256), 256, 0, stream>>>(ei, ycomb,
                                                                  acc, cnt, E);
  finalize1<<<(N * 8 + 255) / 256, 256, 0, stream>>>(acc, cnt, b1l, ycomb, h,
                                                     N);
  // Layer 2
  hipMemsetAsync(acc, 0, (size_t)N * 32 * 4, stream);
  gemm_mfma<<<(N + 127) / 128, 256, 0, stream>>>(h, wb2, ycomb, N, 32, 32);
  edge_agg<<<(int)(((long)E * 32 + 255) / 256), 256, 0, stream>>>(
      ei, ycomb, acc, nullptr, E);
  finalize2<<<(N * 32 + 255) / 256, 256, 0, stream>>>(acc, cnt, b2l, ycomb,
                                                      out, N);
}

// Round 3
// 367.131 us; speedup vs baseline: 1.5347x; 1.1261x over previous
//
#include <hip/hip_runtime.h>
#include <hip/hip_bf16.h>

// GraphSAGE 2-layer. Project-then-aggregate (aggregation is linear):
//   ycomb = x @ [W1l|W1r]^T   (bf16 MFMA GEMM, A loaded global->reg, no LDS)
//   CSR build (once): counting-sort edges by tgt
//   h     = csr_mean(ycomb[:, :32]) + b1l + ycomb[:,32:]
//   ycomb = h @ [W2l|W2r]^T
//   out   = log_softmax(relu(csr_mean(ycomb[:, :32]) + b2l + ycomb[:,32:]))

typedef __attribute__((ext_vector_type(8))) __bf16 bf16x8;
typedef __attribute__((ext_vector_type(4))) float f32x4;

__device__ __forceinline__ bf16x8 ld_a8(const float* p) {
  const float4 u = *reinterpret_cast<const float4*>(p);
  const float4 v = *reinterpret_cast<const float4*>(p + 4);
  bf16x8 r;
  r[0] = (__bf16)u.x; r[1] = (__bf16)u.y; r[2] = (__bf16)u.z; r[3] = (__bf16)u.w;
  r[4] = (__bf16)v.x; r[5] = (__bf16)v.y; r[6] = (__bf16)v.z; r[7] = (__bf16)v.w;
  return r;
}

// Convert [W_l; W_r] (each 32 x K fp32) into WB[64][KP] bf16, zero-padded.
__global__ __launch_bounds__(256) void conv_w(const float* __restrict__ Wl,
                                              const float* __restrict__ Wr,
                                              __bf16* __restrict__ out, int K,
                                              int KP) {
  const int t = blockIdx.x * 256 + threadIdx.x;
  if (t >= 64 * KP) return;
  const int c = t / KP, k = t - c * KP;
  float v = 0.0f;
  if (k < K) v = (c < 32) ? Wl[(long)c * K + k] : Wr[(long)(c - 32) * K + k];
  out[t] = (__bf16)v;
}

// Y[N][64] = X[N][K] @ WB[64][KP]^T. 4 waves; wave owns 32 rows x 64 cols.
__global__ __launch_bounds__(256) void gemm_mfma(const float* __restrict__ X,
                                                 const __bf16* __restrict__ WB,
                                                 float* __restrict__ Y,
                                                 int Nrows, int K, int KP) {
  const int tid = threadIdx.x;
  const int w = tid >> 6, l = tid & 63;
  const int lr = l & 15, lg = l >> 4;
  const long rowbase = (long)blockIdx.x * 128 + (long)w * 32;
  long r0 = rowbase + lr;      if (r0 >= Nrows) r0 = Nrows - 1;
  long r1 = rowbase + 16 + lr; if (r1 >= Nrows) r1 = Nrows - 1;
  const float* px0 = X + r0 * K + lg * 8;
  const float* px1 = X + r1 * K + lg * 8;
  const __bf16* pw = WB + (long)lr * KP + lg * 8;
  const long ws16 = (long)16 * KP;

  f32x4 acc[2][4];
#pragma unroll
  for (int i = 0; i < 2; ++i)
#pragma unroll
    for (int j = 0; j < 4; ++j) acc[i][j] = (f32x4){0.f, 0.f, 0.f, 0.f};

  const int nfull = K >> 5;
  const int krem = K & 31;

  bf16x8 a0, a1, b0, b1, b2, b3;
  a0 = ld_a8(px0);
  a1 = ld_a8(px1);
  b0 = *reinterpret_cast<const bf16x8*>(pw);
  b1 = *reinterpret_cast<const bf16x8*>(pw + ws16);
  b2 = *reinterpret_cast<const bf16x8*>(pw + 2 * ws16);
  b3 = *reinterpret_cast<const bf16x8*>(pw + 3 * ws16);

#define MFMA8()                                                               \
  do {                                                                        \
    acc[0][0] = __builtin_amdgcn_mfma_f32_16x16x32_bf16(a0, b0, acc[0][0], 0, 0, 0); \
    acc[0][1] = __builtin_amdgcn_mfma_f32_16x16x32_bf16(a0, b1, acc[0][1], 0, 0, 0); \
    acc[0][2] = __builtin_amdgcn_mfma_f32_16x16x32_bf16(a0, b2, acc[0][2], 0, 0, 0); \
    acc[0][3] = __builtin_amdgcn_mfma_f32_16x16x32_bf16(a0, b3, acc[0][3], 0, 0, 0); \
    acc[1][0] = __builtin_amdgcn_mfma_f32_16x16x32_bf16(a1, b0, acc[1][0], 0, 0, 0); \
    acc[1][1] = __builtin_amdgcn_mfma_f32_16x16x32_bf16(a1, b1, acc[1][1], 0, 0, 0); \
    acc[1][2] = __builtin_amdgcn_mfma_f32_16x16x32_bf16(a1, b2, acc[1][2], 0, 0, 0); \
    acc[1][3] = __builtin_amdgcn_mfma_f32_16x16x32_bf16(a1, b3, acc[1][3], 0, 0, 0); \
  } while (0)

  for (int s = 1; s < nfull; ++s) {
    const int k0 = s * 32;
    const bf16x8 na0 = ld_a8(px0 + k0);
    const bf16x8 na1 = ld_a8(px1 + k0);
    const bf16x8 nb0 = *reinterpret_cast<const bf16x8*>(pw + k0);
    const bf16x8 nb1 = *reinterpret_cast<const bf16x8*>(pw + ws16 + k0);
    const bf16x8 nb2 = *reinterpret_cast<const bf16x8*>(pw + 2 * ws16 + k0);
    const bf16x8 nb3 = *reinterpret_cast<const bf16x8*>(pw + 3 * ws16 + k0);
    MFMA8();
    a0 = na0; a1 = na1; b0 = nb0; b1 = nb1; b2 = nb2; b3 = nb3;
  }
  MFMA8();

  if (krem) {
    const int k0 = nfull * 32;
    bf16x8 ta0, ta1;
#pragma unroll
    for (int i = 0; i < 8; ++i) {
      const int k = k0 + lg * 8 + i;
      ta0[i] = (k < K) ? (__bf16)px0[k0 + i] : (__bf16)0.0f;
      ta1[i] = (k < K) ? (__bf16)px1[k0 + i] : (__bf16)0.0f;
    }
    a0 = ta0; a1 = ta1;
    b0 = *reinterpret_cast<const bf16x8*>(pw + k0);
    b1 = *reinterpret_cast<const bf16x8*>(pw + ws16 + k0);
    b2 = *reinterpret_cast<const bf16x8*>(pw + 2 * ws16 + k0);
    b3 = *reinterpret_cast<const bf16x8*>(pw + 3 * ws16 + k0);
    MFMA8();
  }
#undef MFMA8

#pragma unroll
  for (int t = 0; t < 2; ++t) {
#pragma unroll
    for (int j = 0; j < 4; ++j) {
      const long R = rowbase + t * 16 + lg * 4 + j;
      if (R < Nrows) {
#pragma unroll
        for (int ct = 0; ct < 4; ++ct)
          Y[R * 64 + ct * 16 + lr] = acc[t][ct][j];
      }
    }
  }
}

// ---------------- CSR build: counting sort edges by tgt ----------------

__global__ __launch_bounds__(256) void hist_deg(const int* __restrict__ ei,
                                                int* __restrict__ deg, int E) {
  const int e = blockIdx.x * 256 + threadIdx.x;
  if (e < E) atomicAdd(&deg[ei[E + e]], 1);
}

// S1: per-2048-tile sums of deg
__global__ __launch_bounds__(256) void scan_tilesum(const int* __restrict__ deg,
                                                    int* __restrict__ tileSum,
                                                    int n) {
  __shared__ int s[256];
  const int b = blockIdx.x, t = threadIdx.x;
  const int base = b * 2048 + t * 8;
  int v = 0;
#pragma unroll
  for (int j = 0; j < 8; ++j) {
    const int i = base + j;
    if (i < n) v += deg[i];
  }
  s[t] = v;
  __syncthreads();
  for (int d = 128; d > 0; d >>= 1) {
    if (t < d) s[t] += s[t + d];
    __syncthreads();
  }
  if (t == 0) tileSum[b] = s[0];
}

// S2: exclusive scan of tile sums (nT <= 64), one wave
__global__ __launch_bounds__(64) void scan_tileoff(const int* __restrict__ tileSum,
                                                   int* __restrict__ tileOff,
                                                   int nT) {
  const int l = threadIdx.x;
  const int v = (l < nT) ? tileSum[l] : 0;
  int inc = v;
#pragma unroll
  for (int d = 1; d < 64; d <<= 1) {
    const int o = __shfl_up(inc, d);
    if (l >= d) inc += o;
  }
  if (l < nT) tileOff[l] = inc - v;
}

// S3: per-tile exclusive scan + tile offset -> global exclusive offsets
__global__ __launch_bounds__(256) void scan_offsets(const int* __restrict__ deg,
                                                    const int* __restrict__ tileOff,
                                                    int* __restrict__ off, int n) {
  __shared__ int warpTot[4];
  const int b = blockIdx.x, t = threadIdx.x;
  const int base = b * 2048 + t * 8;
  int v[8];
  int s = 0;
#pragma unroll
  for (int j = 0; j < 8; ++j) {
    const int i = base + j;
    v[j] = (i < n) ? deg[i] : 0;
    s += v[j];
  }
  const int l = t & 63, w = t >> 6;
  int inc = s;
#pragma unroll
  for (int d = 1; d < 64; d <<= 1) {
    const int o = __shfl_up(inc, d);
    if (l >= d) inc += o;
  }
  if (l == 63) warpTot[w] = inc;
  __syncthreads();
  int wo = 0;
  for (int k = 0; k < w; ++k) wo += warpTot[k];
  int ex = wo + (inc - s) + tileOff[b];
#pragma unroll
  for (int j = 0; j < 8; ++j) {
    const int i = base + j;
    if (i < n) {
      off[i] = ex;
      ex += v[j];
    }
  }
}

__global__ __launch_bounds__(256) void scatter_src(const int* __restrict__ ei,
                                                   const int* __restrict__ off,
                                                   int* __restrict__ fill,
                                                   int* __restrict__ ssrc,
                                                   int E) {
  const int e = blockIdx.x * 256 + threadIdx.x;
  if (e < E) {
    const int t = ei[E + e];
    const int p = off[t] + atomicAdd(&fill[t], 1);
    ssrc[p] = ei[e];
  }
}

// ---------------- fused aggregation ----------------
// 32 lanes per node: mean over CSR neighbors of Y[src][c] (c<32), + bias +
// Y[i][32+c]. Layer 1 writes H; layer 2 applies relu+log_softmax to out.
template <int FINAL>
__global__ __launch_bounds__(256) void agg_fused(
    const int* __restrict__ off, const int* __restrict__ deg,
    const int* __restrict__ ssrc, const float* __restrict__ Y,
    const float* __restrict__ bias, float* __restrict__ out, int N) {
  const int t = blockIdx.x * 256 + threadIdx.x;
  const int i = t >> 5, c = t & 31;
  if (i >= N) return;
  const int st = off[i], d = deg[i];
  float acc = 0.0f;
  int e = 0;
  for (; e + 4 <= d; e += 4) {
    const int s0 = ssrc[st + e + 0];
    const int s1 = ssrc[st + e + 1];
    const int s2 = ssrc[st + e + 2];
    const int s3 = ssrc[st + e + 3];
    acc += Y[(long)s0 * 64 + c] + Y[(long)s1 * 64 + c] +
           Y[(long)s2 * 64 + c] + Y[(long)s3 * 64 + c];
  }
  for (; e < d; ++e) acc += Y[(long)ssrc[st + e] * 64 + c];
  const float mean = acc / fmaxf((float)d, 1.0f);
  float v = mean + bias[c] + Y[(long)i * 64 + 32 + c];
  if (FINAL) {
    v = fmaxf(v, 0.0f);
    float m = v;
#pragma unroll
    for (int dd = 16; dd >= 1; dd >>= 1) m = fmaxf(m, __shfl_xor(m, dd));
    const float ex = __expf(v - m);
    float s = ex;
#pragma unroll
    for (int dd = 16; dd >= 1; dd >>= 1) s += __shfl_xor(s, dd);
    out[(long)i * 32 + c] = (v - m) - __logf(s);
  } else {
    out[(long)i * 32 + c] = v;
  }
}

extern "C" void kernel_launch(void* const* d_in, const int* in_sizes, int n_in,
                              void* d_out, int out_size, void* d_ws,
                              size_t ws_size, hipStream_t stream) {
  const float* x = (const float*)d_in[0];
  const int* ei = (const int*)d_in[1];
  const float* W1l = (const float*)d_in[2];
  const float* b1l = (const float*)d_in[3];
  const float* W1r = (const float*)d_in[4];
  const float* W2l = (const float*)d_in[5];
  const float* b2l = (const float*)d_in[6];
  const float* W2r = (const float*)d_in[7];
  float* out = (float*)d_out;

  const int K1 = 1433;
  const int KP1 = 1440;  // padded, multiple of 8
  const int N = in_sizes[0] / K1;
  const int E = in_sizes[1] / 2;
  const int nTiles = (N + 2047) / 2048;

  char* ws = (char*)d_ws;
  size_t o = 0;
  auto alloc = [&](size_t bytes) {
    void* p = ws + o;
    o += (bytes + 255) & ~(size_t)255;
    return p;
  };
  float* ycomb = (float*)alloc((size_t)N * 64 * 4);
  float* h = (float*)alloc((size_t)N * 32 * 4);
  __bf16* wb1 = (__bf16*)alloc((size_t)64 * KP1 * 2);
  __bf16* wb2 = (__bf16*)alloc((size_t)64 * 32 * 2);
  int* deg = (int*)alloc((size_t)N * 4);
  int* off = (int*)alloc((size_t)N * 4);
  int* fill = (int*)alloc((size_t)N * 4);
  int* ssrc = (int*)alloc((size_t)E * 4);
  int* tileSum = (int*)alloc(64 * 4);
  int* tileOff = (int*)alloc(64 * 4);

  // Weight conversion + CSR build (CSR reused by both layers)
  conv_w<<<(64 * KP1 + 255) / 256, 256, 0, stream>>>(W1l, W1r, wb1, K1, KP1);
  conv_w<<<(64 * 32 + 255) / 256, 256, 0, stream>>>(W2l, W2r, wb2, 32, 32);
  hipMemsetAsync(deg, 0, (size_t)N * 4, stream);
  hipMemsetAsync(fill, 0, (size_t)N * 4, stream);
  hist_deg<<<(E + 255) / 256, 256, 0, stream>>>(ei, deg, E);
  scan_tilesum<<<nTiles, 256, 0, stream>>>(deg, tileSum, N);
  scan_tileoff<<<1, 64, 0, stream>>>(tileSum, tileOff, nTiles);
  scan_offsets<<<nTiles, 256, 0, stream>>>(deg, tileOff, off, N);
  scatter_src<<<(E + 255) / 256, 256, 0, stream>>>(ei, off, fill, ssrc, E);

  // Layer 1
  gemm_mfma<<<(N + 127) / 128, 256, 0, stream>>>(x, wb1, ycomb, N, K1, KP1);
  agg_fused<0><<<(N * 32 + 255) / 256, 256, 0, stream>>>(off, deg, ssrc, ycomb,
                                                         b1l, h, N);
  // Layer 2
  gemm_mfma<<<(N + 127) / 128, 256, 0, stream>>>(h, wb2, ycomb, N, 32, 32);
  agg_fused<1><<<(N * 32 + 255) / 256, 256, 0, stream>>>(off, deg, ssrc, ycomb,
                                                         b2l, out, N);
}

// Round 4
// 351.134 us; speedup vs baseline: 1.6047x; 1.0456x over previous
//
#include <hip/hip_runtime.h>
#include <hip/hip_bf16.h>

// GraphSAGE 2-layer. Project-then-aggregate (aggregation is linear):
//   ycomb = x @ [W1l|W1r]^T   (bf16 MFMA, depth-4 A-prefetch, no LDS)
//   CSR build (once): counting-sort edges by tgt
//   h     = csr_mean(ycomb[:, :32]) + b1l + ycomb[:,32:]
//   ycomb = h @ [W2l|W2r]^T
//   out   = log_softmax(relu(csr_mean(ycomb[:, :32]) + b2l + ycomb[:,32:]))

typedef __attribute__((ext_vector_type(8))) __bf16 bf16x8;
typedef __attribute__((ext_vector_type(4))) float f32x4;

constexpr int K1 = 1433;
constexpr int KP1 = 1440;   // padded K, multiple of 32
constexpr int NFULL = 44;   // 44*32 = 1408 full k-steps
// tail covers k = 1408..1432 (25 elems), B zero-padded to 1440

__device__ __forceinline__ bf16x8 cvt8(const float4 lo, const float4 hi) {
  bf16x8 r;
  r[0] = (__bf16)lo.x; r[1] = (__bf16)lo.y;
  r[2] = (__bf16)lo.z; r[3] = (__bf16)lo.w;
  r[4] = (__bf16)hi.x; r[5] = (__bf16)hi.y;
  r[6] = (__bf16)hi.z; r[7] = (__bf16)hi.w;
  return r;
}

#define MFMA4(af, bi)                                                          \
  do {                                                                         \
    acc[0] = __builtin_amdgcn_mfma_f32_16x16x32_bf16(af, bb[bi][0], acc[0], 0, 0, 0); \
    acc[1] = __builtin_amdgcn_mfma_f32_16x16x32_bf16(af, bb[bi][1], acc[1], 0, 0, 0); \
    acc[2] = __builtin_amdgcn_mfma_f32_16x16x32_bf16(af, bb[bi][2], acc[2], 0, 0, 0); \
    acc[3] = __builtin_amdgcn_mfma_f32_16x16x32_bf16(af, bb[bi][3], acc[3], 0, 0, 0); \
  } while (0)

// Convert [W_l; W_r] (each 32 x K fp32) into WB[64][KP] bf16, zero-padded.
__global__ __launch_bounds__(256) void conv_w(const float* __restrict__ Wl,
                                              const float* __restrict__ Wr,
                                              __bf16* __restrict__ out, int K,
                                              int KP) {
  const int t = blockIdx.x * 256 + threadIdx.x;
  if (t >= 64 * KP) return;
  const int c = t / KP, k = t - c * KP;
  float v = 0.0f;
  if (k < K) v = (c < 32) ? Wl[(long)c * K + k] : Wr[(long)(c - 32) * K + k];
  out[t] = (__bf16)v;
}

// Y[N][64] = X[N][1433] @ WB[64][1440]^T.  4 waves/block; wave owns 16 rows.
// A: global->reg fp32 ring (depth 4) -> cvt bf16. B: bf16 L2-resident ring
// (depth 2). No LDS, no barriers.
__global__ __launch_bounds__(256) void gemm_big(const float* __restrict__ X,
                                                const __bf16* __restrict__ WB,
                                                float* __restrict__ Y,
                                                int Nrows) {
  const int tid = threadIdx.x;
  const int w = tid >> 6, l = tid & 63;
  const int lr = l & 15, lg = l >> 4;
  const long rowbase = (long)blockIdx.x * 64 + (long)w * 16;
  long r0 = rowbase + lr;
  if (r0 >= Nrows) r0 = Nrows - 1;
  const float* px = X + r0 * K1 + lg * 8;
  const __bf16* pw = WB + (long)lr * KP1 + lg * 8;
  const long bstr = (long)16 * KP1;

  f32x4 acc[4];
#pragma unroll
  for (int j = 0; j < 4; ++j) acc[j] = (f32x4){0.f, 0.f, 0.f, 0.f};

  float4 alo[4], ahi[4];
  bf16x8 bb[2][4];
#pragma unroll
  for (int d = 0; d < 4; ++d) {
    alo[d] = *reinterpret_cast<const float4*>(px + d * 32);
    ahi[d] = *reinterpret_cast<const float4*>(px + d * 32 + 4);
  }
#pragma unroll
  for (int d = 0; d < 2; ++d)
#pragma unroll
    for (int t = 0; t < 4; ++t)
      bb[d][t] = *reinterpret_cast<const bf16x8*>(pw + d * 32 + t * bstr);

  // groups 0..9: steps 0..39, always prefetch A(s+4), B(s+2)
#pragma unroll 1
  for (int g = 0; g < 10; ++g) {
#pragma unroll
    for (int s4 = 0; s4 < 4; ++s4) {
      const int s = g * 4 + s4;
      const bf16x8 af = cvt8(alo[s4], ahi[s4]);
      alo[s4] = *reinterpret_cast<const float4*>(px + (s + 4) * 32);
      ahi[s4] = *reinterpret_cast<const float4*>(px + (s + 4) * 32 + 4);
      const int bi = s & 1;
      MFMA4(af, bi);
#pragma unroll
      for (int t = 0; t < 4; ++t)
        bb[bi][t] =
            *reinterpret_cast<const bf16x8*>(pw + (s + 2) * 32 + t * bstr);
    }
  }
  // group 10: steps 40..43, no A prefetch; B prefetch only for s=40,41
#pragma unroll
  for (int s4 = 0; s4 < 4; ++s4) {
    const int s = 40 + s4;
    const bf16x8 af = cvt8(alo[s4], ahi[s4]);
    const int bi = s & 1;
    MFMA4(af, bi);
    if (s4 < 2) {
#pragma unroll
      for (int t = 0; t < 4; ++t)
        bb[bi][t] =
            *reinterpret_cast<const bf16x8*>(pw + (s + 2) * 32 + t * bstr);
    }
  }
  // tail step: k0 = 1408, valid k < 1433 (B zero-padded beyond)
  {
    bf16x8 ta;
#pragma unroll
    for (int i = 0; i < 8; ++i) {
      const int k = NFULL * 32 + lg * 8 + i;
      ta[i] = (k < K1) ? (__bf16)px[NFULL * 32 + i] : (__bf16)0.0f;
    }
    bf16x8 bt[4];
#pragma unroll
    for (int t = 0; t < 4; ++t)
      bt[t] = *reinterpret_cast<const bf16x8*>(pw + NFULL * 32 + t * bstr);
#pragma unroll
    for (int t = 0; t < 4; ++t)
      acc[t] = __builtin_amdgcn_mfma_f32_16x16x32_bf16(ta, bt[t], acc[t], 0, 0, 0);
  }

  // D layout: col = lane&15 (lr), row = lg*4 + reg j
#pragma unroll
  for (int j = 0; j < 4; ++j) {
    const long R = rowbase + lg * 4 + j;
    if (R < Nrows) {
#pragma unroll
      for (int ct = 0; ct < 4; ++ct) Y[R * 64 + ct * 16 + lr] = acc[ct][j];
    }
  }
}

// Y[N][64] = X[N][32] @ WB[64][32]^T, single k-step.
__global__ __launch_bounds__(256) void gemm_small(const float* __restrict__ X,
                                                  const __bf16* __restrict__ WB,
                                                  float* __restrict__ Y,
                                                  int Nrows) {
  const int tid = threadIdx.x;
  const int w = tid >> 6, l = tid & 63;
  const int lr = l & 15, lg = l >> 4;
  const long rowbase = (long)blockIdx.x * 64 + (long)w * 16;
  long r0 = rowbase + lr;
  if (r0 >= Nrows) r0 = Nrows - 1;
  const float* px = X + r0 * 32 + lg * 8;
  const __bf16* pw = WB + lr * 32 + lg * 8;

  const float4 lo = *reinterpret_cast<const float4*>(px);
  const float4 hi = *reinterpret_cast<const float4*>(px + 4);
  const bf16x8 af = cvt8(lo, hi);
  f32x4 acc[4];
#pragma unroll
  for (int j = 0; j < 4; ++j) acc[j] = (f32x4){0.f, 0.f, 0.f, 0.f};
#pragma unroll
  for (int t = 0; t < 4; ++t) {
    const bf16x8 bf = *reinterpret_cast<const bf16x8*>(pw + t * 16 * 32);
    acc[t] = __builtin_amdgcn_mfma_f32_16x16x32_bf16(af, bf, acc[t], 0, 0, 0);
  }
#pragma unroll
  for (int j = 0; j < 4; ++j) {
    const long R = rowbase + lg * 4 + j;
    if (R < Nrows) {
#pragma unroll
      for (int ct = 0; ct < 4; ++ct) Y[R * 64 + ct * 16 + lr] = acc[ct][j];
    }
  }
}

// ---------------- CSR build: counting sort edges by tgt ----------------

__global__ __launch_bounds__(256) void hist_deg(const int* __restrict__ ei,
                                                int* __restrict__ deg, int E) {
  const int e = blockIdx.x * 256 + threadIdx.x;
  if (e < E) atomicAdd(&deg[ei[E + e]], 1);
}

__global__ __launch_bounds__(256) void scan_tilesum(const int* __restrict__ deg,
                                                    int* __restrict__ tileSum,
                                                    int n) {
  __shared__ int s[256];
  const int b = blockIdx.x, t = threadIdx.x;
  const int base = b * 2048 + t * 8;
  int v = 0;
#pragma unroll
  for (int j = 0; j < 8; ++j) {
    const int i = base + j;
    if (i < n) v += deg[i];
  }
  s[t] = v;
  __syncthreads();
  for (int d = 128; d > 0; d >>= 1) {
    if (t < d) s[t] += s[t + d];
    __syncthreads();
  }
  if (t == 0) tileSum[b] = s[0];
}

__global__ __launch_bounds__(64) void scan_tileoff(const int* __restrict__ tileSum,
                                                   int* __restrict__ tileOff,
                                                   int nT) {
  const int l = threadIdx.x;
  const int v = (l < nT) ? tileSum[l] : 0;
  int inc = v;
#pragma unroll
  for (int d = 1; d < 64; d <<= 1) {
    const int o = __shfl_up(inc, d);
    if (l >= d) inc += o;
  }
  if (l < nT) tileOff[l] = inc - v;
}

__global__ __launch_bounds__(256) void scan_offsets(const int* __restrict__ deg,
                                                    const int* __restrict__ tileOff,
                                                    int* __restrict__ off, int n) {
  __shared__ int warpTot[4];
  const int b = blockIdx.x, t = threadIdx.x;
  const int base = b * 2048 + t * 8;
  int v[8];
  int s = 0;
#pragma unroll
  for (int j = 0; j < 8; ++j) {
    const int i = base + j;
    v[j] = (i < n) ? deg[i] : 0;
    s += v[j];
  }
  const int l = t & 63, w = t >> 6;
  int inc = s;
#pragma unroll
  for (int d = 1; d < 64; d <<= 1) {
    const int o = __shfl_up(inc, d);
    if (l >= d) inc += o;
  }
  if (l == 63) warpTot[w] = inc;
  __syncthreads();
  int wo = 0;
  for (int k = 0; k < w; ++k) wo += warpTot[k];
  int ex = wo + (inc - s) + tileOff[b];
#pragma unroll
  for (int j = 0; j < 8; ++j) {
    const int i = base + j;
    if (i < n) {
      off[i] = ex;
      ex += v[j];
    }
  }
}

__global__ __launch_bounds__(256) void scatter_src(const int* __restrict__ ei,
                                                   const int* __restrict__ off,
                                                   int* __restrict__ fill,
                                                   int* __restrict__ ssrc,
                                                   int E) {
  const int e = blockIdx.x * 256 + threadIdx.x;
  if (e < E) {
    const int t = ei[E + e];
    const int p = off[t] + atomicAdd(&fill[t], 1);
    ssrc[p] = ei[e];
  }
}

// ---------------- fused aggregation ----------------
template <int FINAL>
__global__ __launch_bounds__(256) void agg_fused(
    const int* __restrict__ off, const int* __restrict__ deg,
    const int* __restrict__ ssrc, const float* __restrict__ Y,
    const float* __restrict__ bias, float* __restrict__ out, int N) {
  const int t = blockIdx.x * 256 + threadIdx.x;
  const int i = t >> 5, c = t & 31;
  if (i >= N) return;
  const int st = off[i], d = deg[i];
  float acc = 0.0f;
  int e = 0;
  for (; e + 4 <= d; e += 4) {
    const int s0 = ssrc[st + e + 0];
    const int s1 = ssrc[st + e + 1];
    const int s2 = ssrc[st + e + 2];
    const int s3 = ssrc[st + e + 3];
    acc += Y[(long)s0 * 64 + c] + Y[(long)s1 * 64 + c] +
           Y[(long)s2 * 64 + c] + Y[(long)s3 * 64 + c];
  }
  for (; e < d; ++e) acc += Y[(long)ssrc[st + e] * 64 + c];
  const float mean = acc / fmaxf((float)d, 1.0f);
  float v = mean + bias[c] + Y[(long)i * 64 + 32 + c];
  if (FINAL) {
    v = fmaxf(v, 0.0f);
    float m = v;
#pragma unroll
    for (int dd = 16; dd >= 1; dd >>= 1) m = fmaxf(m, __shfl_xor(m, dd));
    const float ex = __expf(v - m);
    float s = ex;
#pragma unroll
    for (int dd = 16; dd >= 1; dd >>= 1) s += __shfl_xor(s, dd);
    out[(long)i * 32 + c] = (v - m) - __logf(s);
  } else {
    out[(long)i * 32 + c] = v;
  }
}

extern "C" void kernel_launch(void* const* d_in, const int* in_sizes, int n_in,
                              void* d_out, int out_size, void* d_ws,
                              size_t ws_size, hipStream_t stream) {
  const float* x = (const float*)d_in[0];
  const int* ei = (const int*)d_in[1];
  const float* W1l = (const float*)d_in[2];
  const float* b1l = (const float*)d_in[3];
  const float* W1r = (const float*)d_in[4];
  const float* W2l = (const float*)d_in[5];
  const float* b2l = (const float*)d_in[6];
  const float* W2r = (const float*)d_in[7];
  float* out = (float*)d_out;

  const int N = in_sizes[0] / K1;
  const int E = in_sizes[1] / 2;
  const int nTiles = (N + 2047) / 2048;

  char* ws = (char*)d_ws;
  size_t o = 0;
  auto alloc = [&](size_t bytes) {
    void* p = ws + o;
    o += (bytes + 255) & ~(size_t)255;
    return p;
  };
  float* ycomb = (float*)alloc((size_t)N * 64 * 4);
  float* h = (float*)alloc((size_t)N * 32 * 4);
  __bf16* wb1 = (__bf16*)alloc((size_t)64 * KP1 * 2);
  __bf16* wb2 = (__bf16*)alloc((size_t)64 * 32 * 2);
  int* deg = (int*)alloc((size_t)N * 4);
  int* off = (int*)alloc((size_t)N * 4);
  int* fill = (int*)alloc((size_t)N * 4);
  int* ssrc = (int*)alloc((size_t)E * 4);
  int* tileSum = (int*)alloc(64 * 4);
  int* tileOff = (int*)alloc(64 * 4);

  conv_w<<<(64 * KP1 + 255) / 256, 256, 0, stream>>>(W1l, W1r, wb1, K1, KP1);
  conv_w<<<(64 * 32 + 255) / 256, 256, 0, stream>>>(W2l, W2r, wb2, 32, 32);
  hipMemsetAsync(deg, 0, (size_t)N * 4, stream);
  hipMemsetAsync(fill, 0, (size_t)N * 4, stream);
  hist_deg<<<(E + 255) / 256, 256, 0, stream>>>(ei, deg, E);
  scan_tilesum<<<nTiles, 256, 0, stream>>>(deg, tileSum, N);
  scan_tileoff<<<1, 64, 0, stream>>>(tileSum, tileOff, nTiles);
  scan_offsets<<<nTiles, 256, 0, stream>>>(deg, tileOff, off, N);
  scatter_src<<<(E + 255) / 256, 256, 0, stream>>>(ei, off, fill, ssrc, E);

  // Layer 1
  gemm_big<<<(N + 63) / 64, 256, 0, stream>>>(x, wb1, ycomb, N);
  agg_fused<0><<<(N * 32 + 255) / 256, 256, 0, stream>>>(off, deg, ssrc, ycomb,
                                                         b1l, h, N);
  // Layer 2
  gemm_small<<<(N + 63) / 64, 256, 0, stream>>>(h, wb2, ycomb, N);
  agg_fused<1><<<(N * 32 + 255) / 256, 256, 0, stream>>>(off, deg, ssrc, ycomb,
                                                         b2l, out, N);
}